// Round 1
// baseline (419.399 us; speedup 1.0000x reference)
//
#include <hip/hip_runtime.h>
#include <hip/hip_fp16.h>

// Problem constants (fixed by the reference):
//   B=32768, N=4, F_IN=512, D=64  -> GEMM [131072 x 512] x [512 x 192]
#define BTOT   32768
#define FIN    512
#define NCOLS  192       // packed k|q|v output columns
#define KSTEPS 16        // 512 / 32
#define NTILES 12        // 192 / 16
// Swizzled weight buffer: [KSTEPS][NTILES][64 lanes][8 halves] = 98304 halves
#define WH_ELEMS (KSTEPS * NTILES * 64 * 8)
#define CHUNK_HALVES (NTILES * 64 * 8)   // 6144 halves per k-step

using half8   = __attribute__((ext_vector_type(8))) _Float16;
using floatx4 = __attribute__((ext_vector_type(4))) float;

// Convert Wk|Wq|Wv (fp32 [512,64] each) into fp16 MFMA B-fragment order.
// B-operand layout for mfma_f32_16x16x32_f16: lane holds B[k=(lane>>4)*8+j][n=lane&15].
__global__ void convert_w_kernel(const float* __restrict__ Wk,
                                 const float* __restrict__ Wq,
                                 const float* __restrict__ Wv,
                                 _Float16* __restrict__ Wh) {
    int idx = blockIdx.x * blockDim.x + threadIdx.x;
    if (idx >= WH_ELEMS) return;
    int j    = idx & 7;
    int lane = (idx >> 3) & 63;
    int t    = (idx >> 9) % NTILES;
    int kk   = idx / CHUNK_HALVES;
    int k = kk * 32 + (lane >> 4) * 8 + j;
    int n = t * 16 + (lane & 15);
    const float* src = (n < 64) ? Wk : (n < 128) ? Wq : Wv;
    Wh[idx] = (_Float16)src[k * 64 + (n & 63)];
}

// Fused projection-GEMM + tiny attention + maxpool.
// Wave = 16 drug rows (4 b's); WG = 4 waves = 16 b's; grid = 2048 WGs.
// NO LDS, NO barriers: the 192 KiB weight buffer is L1/L2-resident (every
// wave on a CU reads the same 24 KiB per k-step pair), so B-fragments are
// loaded directly from global as per-lane-contiguous 16 B dwordx4 loads.
// Waves free-run; only the A (drug) stream touches HBM.
__global__ __launch_bounds__(256) void attn_fused_kernel(
        const float* __restrict__ drug,    // [131072, 512] fp32
        const _Float16* __restrict__ Wh,   // swizzled fp16 weights
        float* __restrict__ out)           // [32768, 64] fp32
{
    const int tid  = threadIdx.x;
    const int wave = tid >> 6;
    const int lane = tid & 63;
    const int quad = lane >> 4;   // A-frag k-subgroup; also b-index in epilogue
    const int l15  = lane & 15;   // A-frag row m; C/D column

    // This lane's A row: m = l15 within the wave's 16-row block.
    const int row = blockIdx.x * 64 + wave * 16 + l15;
    const float* arow = drug + (size_t)row * FIN + quad * 8;
    const half8* wf = (const half8*)Wh + lane;   // + (kk*NTILES + t)*64

    floatx4 acc[NTILES];
#pragma unroll
    for (int t = 0; t < NTILES; ++t) acc[t] = (floatx4){0.f, 0.f, 0.f, 0.f};

    // one-step A prefetch: HBM latency hides under the previous k-step's
    // MFMAs + TLP (no barriers to force convergence).
    float4 a0 = ((const float4*)arow)[0];
    float4 a1 = ((const float4*)arow)[1];

#define KSTEP_BODY(KKI)                                                       \
    do {                                                                      \
        half8 af;                                                             \
        af[0] = (_Float16)a0.x; af[1] = (_Float16)a0.y;                       \
        af[2] = (_Float16)a0.z; af[3] = (_Float16)a0.w;                       \
        af[4] = (_Float16)a1.x; af[5] = (_Float16)a1.y;                       \
        af[6] = (_Float16)a1.z; af[7] = (_Float16)a1.w;                       \
        const half8* bp = wf + (KKI) * (NTILES * 64);                         \
        _Pragma("unroll")                                                     \
        for (int t = 0; t < NTILES; ++t) {                                    \
            half8 bf = bp[t * 64];                                            \
            acc[t] = __builtin_amdgcn_mfma_f32_16x16x32_f16(af, bf, acc[t], 0, 0, 0); \
        }                                                                     \
    } while (0)

#pragma unroll 1
    for (int kk = 0; kk < KSTEPS - 1; ++kk) {
        const float4* ap = (const float4*)(arow + (kk + 1) * 32);
        float4 n0 = ap[0];
        float4 n1 = ap[1];
        KSTEP_BODY(kk);
        a0 = n0; a1 = n1;
    }
    KSTEP_BODY(KSTEPS - 1);
#undef KSTEP_BODY

    // ---- epilogue: per-quad attention over its b ----
    // acc[t] reg r holds C[row = quad*4 + r][col = t*16 + l15]:
    //   tiles 0-3 = k (d = t*16+l15), 4-7 = q, 8-11 = v.
    // quad q's 16 lanes hold all 64 d's for b_local = q, n = reg.
    float p[4][4];
#pragma unroll
    for (int n = 0; n < 4; ++n)
#pragma unroll
        for (int m = 0; m < 4; ++m) {
            float s = 0.f;
#pragma unroll
            for (int t = 0; t < 4; ++t) s += acc[t][n] * acc[4 + t][m];
            p[n][m] = s;
        }

    // reduce the d-dimension across the 16 lanes of this quad
#pragma unroll
    for (int mask = 1; mask < 16; mask <<= 1) {
#pragma unroll
        for (int n = 0; n < 4; ++n)
#pragma unroll
            for (int m = 0; m < 4; ++m)
                p[n][m] += __shfl_xor(p[n][m], mask, 64);
    }

    // softmax over m (no 1/sqrt(d) scaling, matching reference), PV, maxpool over n
    float res[4] = {-INFINITY, -INFINITY, -INFINITY, -INFINITY};
#pragma unroll
    for (int n = 0; n < 4; ++n) {
        float mx = fmaxf(fmaxf(p[n][0], p[n][1]), fmaxf(p[n][2], p[n][3]));
        float e0 = __expf(p[n][0] - mx);
        float e1 = __expf(p[n][1] - mx);
        float e2 = __expf(p[n][2] - mx);
        float e3 = __expf(p[n][3] - mx);
        float inv = 1.f / (e0 + e1 + e2 + e3);
#pragma unroll
        for (int t = 0; t < 4; ++t) {
            float o = (e0 * acc[8 + t][0] + e1 * acc[8 + t][1] +
                       e2 * acc[8 + t][2] + e3 * acc[8 + t][3]) * inv;
            res[t] = fmaxf(res[t], o);
        }
    }

    const int b = blockIdx.x * 16 + wave * 4 + quad;
#pragma unroll
    for (int t = 0; t < 4; ++t)
        out[b * 64 + t * 16 + l15] = res[t];
}

extern "C" void kernel_launch(void* const* d_in, const int* in_sizes, int n_in,
                              void* d_out, int out_size, void* d_ws, size_t ws_size,
                              hipStream_t stream) {
    const float* drug = (const float*)d_in[0];
    const float* Wk   = (const float*)d_in[1];
    const float* Wq   = (const float*)d_in[2];
    const float* Wv   = (const float*)d_in[3];
    float* out = (float*)d_out;
    _Float16* Wh = (_Float16*)d_ws;   // 196608 B of scratch

    convert_w_kernel<<<(WH_ELEMS + 255) / 256, 256, 0, stream>>>(Wk, Wq, Wv, Wh);
    attn_fused_kernel<<<BTOT / 16, 256, 0, stream>>>(drug, Wh, out);
}

// Round 2
// 372.039 us; speedup vs baseline: 1.1273x; 1.1273x over previous
//
#include <hip/hip_runtime.h>
#include <hip/hip_fp16.h>

// Problem constants (fixed by the reference):
//   B=32768, N=4, F_IN=512, D=64  -> GEMM [131072 x 512] x [512 x 192]
#define BTOT   32768
#define FIN    512
#define NCOLS  192       // packed k|q|v output columns
#define KSTEPS 16        // 512 / 32
#define NTILES 12        // 192 / 16
// Swizzled weight buffer: [KSTEPS][NTILES][64 lanes][8 halves] = 98304 halves
#define WH_ELEMS (KSTEPS * NTILES * 64 * 8)
#define CHUNK_HALVES (NTILES * 64 * 8)   // 6144 halves = 12288 B per k-step
#define CHUNK_BYTES  (CHUNK_HALVES * 2)

using half8   = __attribute__((ext_vector_type(8))) _Float16;
using floatx4 = __attribute__((ext_vector_type(4))) float;

// Async global->LDS, 16 B per lane. LDS dest is wave-uniform base + lane*16.
#define GLOAD_LDS16(gp, lp)                                                  \
    __builtin_amdgcn_global_load_lds(                                        \
        (const __attribute__((address_space(1))) void*)(gp),                 \
        (__attribute__((address_space(3))) void*)(lp), 16, 0, 0)

// Convert Wk|Wq|Wv (fp32 [512,64] each) into fp16 MFMA B-fragment order.
// B-operand layout for mfma_f32_16x16x32_f16: lane holds B[k=(lane>>4)*8+j][n=lane&15].
__global__ void convert_w_kernel(const float* __restrict__ Wk,
                                 const float* __restrict__ Wq,
                                 const float* __restrict__ Wv,
                                 _Float16* __restrict__ Wh) {
    int idx = blockIdx.x * blockDim.x + threadIdx.x;
    if (idx >= WH_ELEMS) return;
    int j    = idx & 7;
    int lane = (idx >> 3) & 63;
    int t    = (idx >> 9) % NTILES;
    int kk   = idx / CHUNK_HALVES;
    int k = kk * 32 + (lane >> 4) * 8 + j;
    int n = t * 16 + (lane & 15);
    const float* src = (n < 64) ? Wk : (n < 128) ? Wq : Wv;
    Wh[idx] = (_Float16)src[k * 64 + (n & 63)];
}

// Fused projection-GEMM + tiny attention + maxpool.
// Wave = 16 drug rows (4 b's); WG = 4 waves = 16 b's; grid = 2048 WGs.
//
// Weight staging: double-buffered LDS at 1-k-step granularity (2 x 12 KiB),
// raw s_barrier + counted s_waitcnt vmcnt(3) (T3/T4): stage(k+2) is issued
// at the end of iter k and awaited at the top of iter k+2, so 3 staging
// loads stay in flight across every barrier -- the compiler's vmcnt(0)
// drain before __syncthreads() is eliminated entirely.
__global__ __launch_bounds__(256) void attn_fused_kernel(
        const float* __restrict__ drug,    // [131072, 512] fp32
        const _Float16* __restrict__ Wh,   // swizzled fp16 weights
        float* __restrict__ out)           // [32768, 64] fp32
{
    __shared__ __align__(16) char lds[2 * CHUNK_BYTES];   // 24576 B -> 6 blocks/CU

    const int tid  = threadIdx.x;
    const int wave = tid >> 6;
    const int lane = tid & 63;
    const int quad = lane >> 4;   // A-frag k-subgroup; also b-index in epilogue
    const int l15  = lane & 15;   // A-frag row m; C/D column

    // This lane's A row: m = l15 within the wave's 16-row block.
    const int row = blockIdx.x * 64 + wave * 16 + l15;
    const float* arow = drug + (size_t)row * FIN + quad * 8;
    const char* gW = (const char*)Wh;

    floatx4 acc[NTILES];
#pragma unroll
    for (int t = 0; t < NTILES; ++t) acc[t] = (floatx4){0.f, 0.f, 0.f, 0.f};

    // Stage k-step K's 12288 B chunk into LDS half (K&1).
    // 3 instrs/wave x 4 waves x 1024 B = 12288 B, linear copy.
#define STAGE(K)                                                             \
    do {                                                                     \
        const char* _s = gW + (size_t)(K) * CHUNK_BYTES;                     \
        char* _d = lds + ((K) & 1) * CHUNK_BYTES;                            \
        _Pragma("unroll")                                                    \
        for (int _i = 0; _i < 3; ++_i) {                                     \
            const int _off = (wave + 4 * _i) * 1024;                         \
            GLOAD_LDS16(_s + _off + lane * 16, _d + _off);                   \
        }                                                                    \
    } while (0)

    // Prologue issue order (vmcnt bookkeeping): st0(3), A0(2), st1(3).
    STAGE(0);
    float4 a0 = ((const float4*)arow)[0];
    float4 a1 = ((const float4*)arow)[1];
    STAGE(1);

#pragma unroll
    for (int k = 0; k < KSTEPS; ++k) {
        // At loop top, outstanding (oldest->newest): st(k)(3), A(k)(2), st(k+1)(3).
        // vmcnt(3) waits st(k)+A(k), leaves st(k+1) in flight across the barrier.
        if (k < KSTEPS - 1)
            asm volatile("s_waitcnt vmcnt(3)" ::: "memory");
        else
            asm volatile("s_waitcnt vmcnt(0)" ::: "memory");
        asm volatile("" ::: "memory");
        __builtin_amdgcn_s_barrier();       // buf[k&1] staged by ALL waves
        asm volatile("" ::: "memory");

        // Prefetch next A (compiler inserts its own correctly-counted waits).
        float4 n0, n1;
        if (k < KSTEPS - 1) {
            const float4* ap = (const float4*)(arow + (k + 1) * 32);
            n0 = ap[0];
            n1 = ap[1];
        }

        half8 af;
        af[0] = (_Float16)a0.x; af[1] = (_Float16)a0.y;
        af[2] = (_Float16)a0.z; af[3] = (_Float16)a0.w;
        af[4] = (_Float16)a1.x; af[5] = (_Float16)a1.y;
        af[6] = (_Float16)a1.z; af[7] = (_Float16)a1.w;

        const _Float16* lh = (const _Float16*)(lds + (k & 1) * CHUNK_BYTES);
#pragma unroll
        for (int t = 0; t < NTILES; ++t) {
            half8 bf = *((const half8*)(lh + (t * 64 + lane) * 8));
            acc[t] = __builtin_amdgcn_mfma_f32_16x16x32_f16(af, bf, acc[t], 0, 0, 0);
        }

        if (k < KSTEPS - 2) {
            asm volatile("" ::: "memory");
            __builtin_amdgcn_s_barrier();   // all waves done reading buf[k&1]
            asm volatile("" ::: "memory");
            STAGE(k + 2);                   // overwrite it; awaited at iter k+2
        }
        a0 = n0; a1 = n1;
    }
#undef STAGE

    // ---- epilogue: per-quad attention over its b ----
    // acc[t] reg r holds C[row = quad*4 + r][col = t*16 + l15]:
    //   tiles 0-3 = k (d = t*16+l15), 4-7 = q, 8-11 = v.
    // quad q's 16 lanes hold all 64 d's for b_local = q, n = reg.
    float p[4][4];
#pragma unroll
    for (int n = 0; n < 4; ++n)
#pragma unroll
        for (int m = 0; m < 4; ++m) {
            float s = 0.f;
#pragma unroll
            for (int t = 0; t < 4; ++t) s += acc[t][n] * acc[4 + t][m];
            p[n][m] = s;
        }

    // reduce the d-dimension across the 16 lanes of this quad
#pragma unroll
    for (int mask = 1; mask < 16; mask <<= 1) {
#pragma unroll
        for (int n = 0; n < 4; ++n)
#pragma unroll
            for (int m = 0; m < 4; ++m)
                p[n][m] += __shfl_xor(p[n][m], mask, 64);
    }

    // softmax over m (no 1/sqrt(d) scaling, matching reference), PV, maxpool over n
    float res[4] = {-INFINITY, -INFINITY, -INFINITY, -INFINITY};
#pragma unroll
    for (int n = 0; n < 4; ++n) {
        float mx = fmaxf(fmaxf(p[n][0], p[n][1]), fmaxf(p[n][2], p[n][3]));
        float e0 = __expf(p[n][0] - mx);
        float e1 = __expf(p[n][1] - mx);
        float e2 = __expf(p[n][2] - mx);
        float e3 = __expf(p[n][3] - mx);
        float inv = 1.f / (e0 + e1 + e2 + e3);
#pragma unroll
        for (int t = 0; t < 4; ++t) {
            float o = (e0 * acc[8 + t][0] + e1 * acc[8 + t][1] +
                       e2 * acc[8 + t][2] + e3 * acc[8 + t][3]) * inv;
            res[t] = fmaxf(res[t], o);
        }
    }

    const int b = blockIdx.x * 16 + wave * 4 + quad;
#pragma unroll
    for (int t = 0; t < 4; ++t)
        out[b * 64 + t * 16 + l15] = res[t];
}

extern "C" void kernel_launch(void* const* d_in, const int* in_sizes, int n_in,
                              void* d_out, int out_size, void* d_ws, size_t ws_size,
                              hipStream_t stream) {
    const float* drug = (const float*)d_in[0];
    const float* Wk   = (const float*)d_in[1];
    const float* Wq   = (const float*)d_in[2];
    const float* Wv   = (const float*)d_in[3];
    float* out = (float*)d_out;
    _Float16* Wh = (_Float16*)d_ws;   // 196608 B of scratch

    convert_w_kernel<<<(WH_ELEMS + 255) / 256, 256, 0, stream>>>(Wk, Wq, Wv, Wh);
    attn_fused_kernel<<<BTOT / 16, 256, 0, stream>>>(drug, Wh, out);
}